// Round 1
// baseline (1012.541 us; speedup 1.0000x reference)
//
#include <hip/hip_runtime.h>
#include <stdint.h>

// R1: full fp16-MFMA pipeline: convert -> QKV GEMM(+fused RoPE) -> flash attn -> out GEMM.
// m97-structure GEMM (128x128 tile, BK=64, global_load_lds w16, 2-barrier loop).
// ws layout (peak 128 MiB): [0]hs16(32M) [32M]wqkvt(48M) [80M]q16(32M) [112M]k16(8M) [120M]v16t(8M)
// after QKV gemm: region0 reused for wo_t, region1 for attn_out.

#define NB    2
#define SEQ   2048
#define HIDD  4096
#define NHQ   32
#define NKVH  8
#define DHEAD 128
#define NQK   (NHQ * DHEAD)        // 4096
#define NKVD  (NKVH * DHEAD)       // 1024
#define NTOT  (NQK + 2 * NKVD)     // 6144
#define MROWS (NB * SEQ)           // 4096

typedef unsigned short u16;
typedef _Float16 half8 __attribute__((ext_vector_type(8)));
typedef float f32x4v __attribute__((ext_vector_type(4)));

static __device__ __forceinline__ u16 f2h(float x) {
  _Float16 h = (_Float16)x;
  return __builtin_bit_cast(u16, h);
}

static __device__ __forceinline__ void load_lds16(const void* g, const void* l) {
  __builtin_amdgcn_global_load_lds(
      (const __attribute__((address_space(1))) void*)(uintptr_t)g,
      (__attribute__((address_space(3))) void*)(uintptr_t)l, 16, 0, 0);
}

// ---------------- fp32 -> fp16 convert (vectorized, grid-stride) ----------------
__global__ __launch_bounds__(256) void k_conv_hs(const float* __restrict__ in,
                                                 u16* __restrict__ out, int n8) {
  int idx = blockIdx.x * 256 + threadIdx.x;
  int stride = gridDim.x * 256;
  for (int i = idx; i < n8; i += stride) {
    const float4* p = (const float4*)(in + (size_t)i * 8);
    float4 a = p[0], b = p[1];
    union { u16 us[8]; int4 v; } t;
    t.us[0] = f2h(a.x); t.us[1] = f2h(a.y); t.us[2] = f2h(a.z); t.us[3] = f2h(a.w);
    t.us[4] = f2h(b.x); t.us[5] = f2h(b.y); t.us[6] = f2h(b.z); t.us[7] = f2h(b.w);
    *(int4*)(out + (size_t)i * 8) = t.v;
  }
}

// ------------- fp32 [R][C] -> fp16 [C][R] tiled transpose+convert ---------------
__global__ __launch_bounds__(256) void k_transpose_f16(const float* __restrict__ in,
                                                       u16* __restrict__ out, int R, int C) {
  __shared__ float tile[64][65];
  int tid = threadIdx.x;
  int c0 = blockIdx.x * 64, r0 = blockIdx.y * 64;
#pragma unroll
  for (int i = 0; i < 4; ++i) {
    int idx = i * 256 + tid;
    int rr = idx >> 4, cc = (idx & 15) * 4;
    float4 v = *(const float4*)&in[(size_t)(r0 + rr) * C + c0 + cc];
    tile[rr][cc] = v.x; tile[rr][cc + 1] = v.y; tile[rr][cc + 2] = v.z; tile[rr][cc + 3] = v.w;
  }
  __syncthreads();
#pragma unroll
  for (int i = 0; i < 4; ++i) {
    int idx = i * 256 + tid;
    int cc = idx >> 4, rr = (idx & 15) * 4;
    union { u16 us[4]; unsigned long long ll; } t;
#pragma unroll
    for (int j = 0; j < 4; ++j) t.us[j] = f2h(tile[rr + j][cc]);
    *(unsigned long long*)&out[(size_t)(c0 + cc) * R + r0 + rr] = t.ll;
  }
}

// ---------------- fp16 MFMA GEMM, m97 structure ----------------
// A [M][K] f16 row-major; Bt [N][K] f16 (i.e. B transposed). 128x128 tile, BK=64.
// MODE 0: QKV epilogue (fused neox RoPE, scatter to q/k/v buffers; v transposed [b,h,d,s])
// MODE 1: plain fp32 store to Cout [M][N]
template <int MODE>
__global__ __launch_bounds__(256, 2) void k_gemm(
    const u16* __restrict__ A, const u16* __restrict__ Bt, int M, int N, int K,
    const int* __restrict__ positions, u16* __restrict__ qout, u16* __restrict__ kout,
    u16* __restrict__ vout, float* __restrict__ Cout) {
  __shared__ u16 As[128 * 64];
  __shared__ u16 Bs[128 * 64];
  const int tid = threadIdx.x;
  const int w = tid >> 6, lane = tid & 63;
  const int lgrp = lane >> 4, l15 = lane & 15;
  const int wr = w >> 1, wc = w & 1;
  const int m0 = blockIdx.y * 128, n0 = blockIdx.x * 128;
  const int srow = lane >> 3, scol = (lane & 7) * 8;
  f32x4v acc[4][4] = {};

  for (int k0 = 0; k0 < K; k0 += 64) {
    __syncthreads();
#pragma unroll
    for (int i = 0; i < 4; ++i) {
      int chunk = w * 4 + i;            // wave-uniform
      int row = chunk * 8 + srow;       // 0..127
      load_lds16(A + (size_t)(m0 + row) * K + k0 + scol, (const char*)As + chunk * 1024);
      load_lds16(Bt + (size_t)(n0 + row) * K + k0 + scol, (const char*)Bs + chunk * 1024);
    }
    __syncthreads();  // compiler drains vmcnt(0) before s_barrier
#pragma unroll
    for (int kf = 0; kf < 2; ++kf) {
      half8 a[4], b[4];
#pragma unroll
      for (int rf = 0; rf < 4; ++rf)
        a[rf] = *(const half8*)&As[(wr * 64 + rf * 16 + l15) * 64 + kf * 32 + lgrp * 8];
#pragma unroll
      for (int cf = 0; cf < 4; ++cf) {
        int gf = wc * 2 + (cf & 1) + (cf >> 1) * 4;  // RoPE-pair swizzle: cf<->cf+2 is d<->d+64
        b[cf] = *(const half8*)&Bs[(gf * 16 + l15) * 64 + kf * 32 + lgrp * 8];
      }
#pragma unroll
      for (int rf = 0; rf < 4; ++rf)
#pragma unroll
        for (int cf = 0; cf < 4; ++cf)
          acc[rf][cf] = __builtin_amdgcn_mfma_f32_16x16x32_f16(a[rf], b[cf], acc[rf][cf], 0, 0, 0);
    }
  }

  if (MODE == 1) {
#pragma unroll
    for (int rf = 0; rf < 4; ++rf)
#pragma unroll
      for (int cf = 0; cf < 4; ++cf) {
        int gf = wc * 2 + (cf & 1) + (cf >> 1) * 4;
        int col = n0 + gf * 16 + l15;
#pragma unroll
        for (int r = 0; r < 4; ++r) {
          int row = m0 + wr * 64 + rf * 16 + lgrp * 4 + r;
          Cout[(size_t)row * N + col] = acc[rf][cf][r];
        }
      }
  } else {
    const float FREQF = -0.14391156642f;  // -ln(10000)/64
#pragma unroll
    for (int rf = 0; rf < 4; ++rf) {
#pragma unroll
      for (int r = 0; r < 4; ++r) {
        int row = m0 + wr * 64 + rf * 16 + lgrp * 4 + r;
        int b_ = row >> 11, s = row & (SEQ - 1);
        if (n0 < NQK + NKVD) {  // q or k region: apply RoPE
          float pos = (float)positions[row];
#pragma unroll
          for (int cf = 0; cf < 2; ++cf) {
            int gf = wc * 2 + cf;
            int d1 = gf * 16 + l15;  // 0..63
            float ang = pos * expf((float)d1 * FREQF);
            float sn, cs;
            sincosf(ang, &sn, &cs);
            float x1 = acc[rf][cf][r], x2 = acc[rf][cf + 2][r];
            float o1 = x1 * cs - x2 * sn;
            float o2 = x1 * sn + x2 * cs;
            if (n0 < NQK) {
              int h = n0 >> 7;
              size_t base = (((size_t)b_ * NHQ + h) * SEQ + s) * DHEAD;
              qout[base + d1] = f2h(o1);
              qout[base + d1 + 64] = f2h(o2);
            } else {
              int h = (n0 - NQK) >> 7;
              size_t base = (((size_t)b_ * NKVH + h) * SEQ + s) * DHEAD;
              kout[base + d1] = f2h(o1);
              kout[base + d1 + 64] = f2h(o2);
            }
          }
        } else {  // v region: store transposed [b][h][d][s]
          int h = (n0 - NQK - NKVD) >> 7;
          size_t base = ((size_t)b_ * NKVH + h) * DHEAD * SEQ;
#pragma unroll
          for (int cf = 0; cf < 4; ++cf) {
            int gf = wc * 2 + (cf & 1) + (cf >> 1) * 4;
            int d = gf * 16 + l15;
            vout[base + (size_t)d * SEQ + s] = f2h(acc[rf][cf][r]);
          }
        }
      }
    }
  }
}

// ---------------- GQA causal flash attention, fp16 MFMA / fp32 softmax ----------------
// Q [b][h][s][d]; K [b][hk][s][d]; Vt [b][hk][d][s]. Out [b][s][h*128+d] f16.
// Block: one (b, h, 64-row q-tile). 4 waves x 16 q-rows. KV tile = 64.
__global__ __launch_bounds__(256, 2) void k_attn(const u16* __restrict__ Q,
                                                 const u16* __restrict__ Kc,
                                                 const u16* __restrict__ Vct,
                                                 u16* __restrict__ Oout) {
  __shared__ u16 Ks[64 * 136];   // [kv][d], pad 8 -> 2-way banks
  __shared__ u16 Vt[128 * 72];   // [d][kv], pad 8
  __shared__ u16 Pl[64 * 72];    // [q][kv], pad 8
  const int qt = blockIdx.x, h = blockIdx.y, b = blockIdx.z;
  const int hk = h >> 2;  // GQA group = 4
  const int tid = threadIdx.x, w = tid >> 6, lane = tid & 63;
  const int lgrp = lane >> 4, l15 = lane & 15;
  const int q0 = qt * 64;
  const size_t qbase = ((size_t)b * NHQ + h) * SEQ * DHEAD;
  const size_t kbase = ((size_t)b * NKVH + hk) * SEQ * DHEAD;
  const size_t vtbase = ((size_t)b * NKVH + hk) * DHEAD * SEQ;

  half8 qf[4];
  {
    int qrow = q0 + w * 16 + l15;
#pragma unroll
    for (int df = 0; df < 4; ++df)
      qf[df] = *(const half8*)&Q[qbase + (size_t)qrow * DHEAD + df * 32 + lgrp * 8];
  }
  f32x4v O[8] = {};
  float mrow[4], lrow[4];
#pragma unroll
  for (int r = 0; r < 4; ++r) { mrow[r] = -3.0e38f; lrow[r] = 0.f; }

  for (int t = 0; t <= qt; ++t) {
    const int kv0 = t * 64;
    __syncthreads();
#pragma unroll
    for (int i = 0; i < 4; ++i) {  // stage K tile [64][128]
      int idx = i * 256 + tid;
      int kv = idx >> 4, c = idx & 15;
      int4 val = *(const int4*)&Kc[kbase + (size_t)(kv0 + kv) * DHEAD + c * 8];
      *(int4*)&Ks[kv * 136 + c * 8] = val;
    }
#pragma unroll
    for (int i = 0; i < 4; ++i) {  // stage V^T tile [128][64] (already transposed in global)
      int idx = i * 256 + tid;
      int d = idx >> 3, c = idx & 7;
      int4 val = *(const int4*)&Vct[vtbase + (size_t)d * SEQ + kv0 + c * 8];
      *(int4*)&Vt[d * 72 + c * 8] = val;
    }
    __syncthreads();

    f32x4v sa[4] = {};
#pragma unroll
    for (int kvf = 0; kvf < 4; ++kvf)
#pragma unroll
      for (int df = 0; df < 4; ++df) {
        half8 kb = *(const half8*)&Ks[(kvf * 16 + l15) * 136 + df * 32 + lgrp * 8];
        sa[kvf] = __builtin_amdgcn_mfma_f32_16x16x32_f16(qf[df], kb, sa[kvf], 0, 0, 0);
      }

    const float scale = 0.08838834764831845f;  // 1/sqrt(128)
#pragma unroll
    for (int r = 0; r < 4; ++r) {
      const int qa = q0 + w * 16 + lgrp * 4 + r;
      float sv[4];
      float mx = -3.0e38f;
#pragma unroll
      for (int kvf = 0; kvf < 4; ++kvf) {
        float x = sa[kvf][r] * scale;
        int ka = kv0 + kvf * 16 + l15;
        x = (ka > qa) ? -3.0e38f : x;  // causal mask (only bites on diagonal tile)
        sv[kvf] = x;
        mx = fmaxf(mx, x);
      }
#pragma unroll
      for (int off = 1; off < 16; off <<= 1) mx = fmaxf(mx, __shfl_xor(mx, off, 64));
      float mnew = fmaxf(mrow[r], mx);
      float alpha = __expf(mrow[r] - mnew);
      mrow[r] = mnew;
      float rs = 0.f;
#pragma unroll
      for (int kvf = 0; kvf < 4; ++kvf) {
        float p = __expf(sv[kvf] - mnew);
        sv[kvf] = p;
        rs += p;
      }
#pragma unroll
      for (int off = 1; off < 16; off <<= 1) rs += __shfl_xor(rs, off, 64);
      lrow[r] = lrow[r] * alpha + rs;
#pragma unroll
      for (int nf = 0; nf < 8; ++nf) O[nf][r] *= alpha;
#pragma unroll
      for (int kvf = 0; kvf < 4; ++kvf)
        Pl[(w * 16 + lgrp * 4 + r) * 72 + kvf * 16 + l15] = f2h(sv[kvf]);
    }

    half8 pa[2];
#pragma unroll
    for (int k2 = 0; k2 < 2; ++k2)
      pa[k2] = *(const half8*)&Pl[(w * 16 + l15) * 72 + k2 * 32 + lgrp * 8];
#pragma unroll
    for (int nf = 0; nf < 8; ++nf)
#pragma unroll
      for (int k2 = 0; k2 < 2; ++k2) {
        half8 vb = *(const half8*)&Vt[(nf * 16 + l15) * 72 + k2 * 32 + lgrp * 8];
        O[nf] = __builtin_amdgcn_mfma_f32_16x16x32_f16(pa[k2], vb, O[nf], 0, 0, 0);
      }
  }

#pragma unroll
  for (int r = 0; r < 4; ++r) {
    float inv = 1.0f / lrow[r];
    int s = q0 + w * 16 + lgrp * 4 + r;
    size_t obase = ((size_t)b * SEQ + s) * NQK + h * DHEAD;
#pragma unroll
    for (int nf = 0; nf < 8; ++nf) Oout[obase + nf * 16 + l15] = f2h(O[nf][r] * inv);
  }
}

// ---------------- launch ----------------
extern "C" void kernel_launch(void* const* d_in, const int* in_sizes, int n_in,
                              void* d_out, int out_size, void* d_ws, size_t ws_size,
                              hipStream_t stream) {
  const float* hs = (const float*)d_in[0];
  const float* wqkv = (const float*)d_in[1];
  const float* wo = (const float*)d_in[2];
  const int* positions = (const int*)d_in[3];
  float* out = (float*)d_out;
  char* ws = (char*)d_ws;

  u16* hs16  = (u16*)(ws);                    // 33,554,432 B
  u16* wqkvt = (u16*)(ws + 33554432);         // 50,331,648 B
  u16* q16   = (u16*)(ws + 83886080);         // 33,554,432 B
  u16* k16   = (u16*)(ws + 117440512);        //  8,388,608 B
  u16* v16t  = (u16*)(ws + 125829120);        //  8,388,608 B (end: 128 MiB)
  u16* wot    = (u16*)(ws);                   // reuse region 0 (hs16 dead after QKV gemm)
  u16* attn16 = (u16*)(ws + 33554432);        // reuse region 1 (wqkvt dead after QKV gemm)

  k_conv_hs<<<2048, 256, 0, stream>>>(hs, hs16, MROWS * HIDD / 8);
  k_transpose_f16<<<dim3(NTOT / 64, HIDD / 64), 256, 0, stream>>>(wqkv, wqkvt, HIDD, NTOT);
  k_gemm<0><<<dim3(NTOT / 128, MROWS / 128), 256, 0, stream>>>(
      hs16, wqkvt, MROWS, NTOT, HIDD, positions, q16, k16, v16t, nullptr);
  k_transpose_f16<<<dim3(HIDD / 64, NQK / 64), 256, 0, stream>>>(wo, wot, NQK, HIDD);
  k_attn<<<dim3(SEQ / 64, NHQ, NB), 256, 0, stream>>>(q16, k16, v16t, attn16);
  k_gemm<1><<<dim3(HIDD / 128, MROWS / 128), 256, 0, stream>>>(
      attn16, wot, MROWS, HIDD, NQK, nullptr, nullptr, nullptr, nullptr, out);
}

// Round 2
// 881.678 us; speedup vs baseline: 1.1484x; 1.1484x over previous
//
#include <hip/hip_runtime.h>
#include <stdint.h>

// R2: attn rework: 4 blocks/CU (P aliased into Ks, LDS 36KB, launch_bounds(256,4)),
// balanced q-tile pairing {i,31-i} -> uniform 33 tiles/block, grid=1024 (=4/CU exactly),
// XCD swizzle, diagonal-only masking, setprio around MFMA. GEMMs unchanged from R1.
// ws layout (peak 128 MiB): [0]hs16(32M) [32M]wqkvt(48M) [80M]q16(32M) [112M]k16(8M) [120M]v16t(8M)

#define NB    2
#define SEQ   2048
#define HIDD  4096
#define NHQ   32
#define NKVH  8
#define DHEAD 128
#define NQK   (NHQ * DHEAD)        // 4096
#define NKVD  (NKVH * DHEAD)       // 1024
#define NTOT  (NQK + 2 * NKVD)     // 6144
#define MROWS (NB * SEQ)           // 4096

typedef unsigned short u16;
typedef _Float16 half8 __attribute__((ext_vector_type(8)));
typedef float f32x4v __attribute__((ext_vector_type(4)));

static __device__ __forceinline__ u16 f2h(float x) {
  _Float16 h = (_Float16)x;
  return __builtin_bit_cast(u16, h);
}

static __device__ __forceinline__ void load_lds16(const void* g, const void* l) {
  __builtin_amdgcn_global_load_lds(
      (const __attribute__((address_space(1))) void*)(uintptr_t)g,
      (__attribute__((address_space(3))) void*)(uintptr_t)l, 16, 0, 0);
}

// ---------------- fp32 -> fp16 convert (vectorized, grid-stride) ----------------
__global__ __launch_bounds__(256) void k_conv_hs(const float* __restrict__ in,
                                                 u16* __restrict__ out, int n8) {
  int idx = blockIdx.x * 256 + threadIdx.x;
  int stride = gridDim.x * 256;
  for (int i = idx; i < n8; i += stride) {
    const float4* p = (const float4*)(in + (size_t)i * 8);
    float4 a = p[0], b = p[1];
    union { u16 us[8]; int4 v; } t;
    t.us[0] = f2h(a.x); t.us[1] = f2h(a.y); t.us[2] = f2h(a.z); t.us[3] = f2h(a.w);
    t.us[4] = f2h(b.x); t.us[5] = f2h(b.y); t.us[6] = f2h(b.z); t.us[7] = f2h(b.w);
    *(int4*)(out + (size_t)i * 8) = t.v;
  }
}

// ------------- fp32 [R][C] -> fp16 [C][R] tiled transpose+convert ---------------
__global__ __launch_bounds__(256) void k_transpose_f16(const float* __restrict__ in,
                                                       u16* __restrict__ out, int R, int C) {
  __shared__ float tile[64][65];
  int tid = threadIdx.x;
  int c0 = blockIdx.x * 64, r0 = blockIdx.y * 64;
#pragma unroll
  for (int i = 0; i < 4; ++i) {
    int idx = i * 256 + tid;
    int rr = idx >> 4, cc = (idx & 15) * 4;
    float4 v = *(const float4*)&in[(size_t)(r0 + rr) * C + c0 + cc];
    tile[rr][cc] = v.x; tile[rr][cc + 1] = v.y; tile[rr][cc + 2] = v.z; tile[rr][cc + 3] = v.w;
  }
  __syncthreads();
#pragma unroll
  for (int i = 0; i < 4; ++i) {
    int idx = i * 256 + tid;
    int cc = idx >> 4, rr = (idx & 15) * 4;
    union { u16 us[4]; unsigned long long ll; } t;
#pragma unroll
    for (int j = 0; j < 4; ++j) t.us[j] = f2h(tile[rr + j][cc]);
    *(unsigned long long*)&out[(size_t)(c0 + cc) * R + r0 + rr] = t.ll;
  }
}

// ---------------- fp16 MFMA GEMM, m97 structure (unchanged from R1) ----------------
template <int MODE>
__global__ __launch_bounds__(256, 2) void k_gemm(
    const u16* __restrict__ A, const u16* __restrict__ Bt, int M, int N, int K,
    const int* __restrict__ positions, u16* __restrict__ qout, u16* __restrict__ kout,
    u16* __restrict__ vout, float* __restrict__ Cout) {
  __shared__ u16 As[128 * 64];
  __shared__ u16 Bs[128 * 64];
  const int tid = threadIdx.x;
  const int w = tid >> 6, lane = tid & 63;
  const int lgrp = lane >> 4, l15 = lane & 15;
  const int wr = w >> 1, wc = w & 1;
  const int m0 = blockIdx.y * 128, n0 = blockIdx.x * 128;
  const int srow = lane >> 3, scol = (lane & 7) * 8;
  f32x4v acc[4][4] = {};

  for (int k0 = 0; k0 < K; k0 += 64) {
    __syncthreads();
#pragma unroll
    for (int i = 0; i < 4; ++i) {
      int chunk = w * 4 + i;            // wave-uniform
      int row = chunk * 8 + srow;       // 0..127
      load_lds16(A + (size_t)(m0 + row) * K + k0 + scol, (const char*)As + chunk * 1024);
      load_lds16(Bt + (size_t)(n0 + row) * K + k0 + scol, (const char*)Bs + chunk * 1024);
    }
    __syncthreads();
#pragma unroll
    for (int kf = 0; kf < 2; ++kf) {
      half8 a[4], b[4];
#pragma unroll
      for (int rf = 0; rf < 4; ++rf)
        a[rf] = *(const half8*)&As[(wr * 64 + rf * 16 + l15) * 64 + kf * 32 + lgrp * 8];
#pragma unroll
      for (int cf = 0; cf < 4; ++cf) {
        int gf = wc * 2 + (cf & 1) + (cf >> 1) * 4;  // RoPE-pair swizzle: cf<->cf+2 is d<->d+64
        b[cf] = *(const half8*)&Bs[(gf * 16 + l15) * 64 + kf * 32 + lgrp * 8];
      }
#pragma unroll
      for (int rf = 0; rf < 4; ++rf)
#pragma unroll
        for (int cf = 0; cf < 4; ++cf)
          acc[rf][cf] = __builtin_amdgcn_mfma_f32_16x16x32_f16(a[rf], b[cf], acc[rf][cf], 0, 0, 0);
    }
  }

  if (MODE == 1) {
#pragma unroll
    for (int rf = 0; rf < 4; ++rf)
#pragma unroll
      for (int cf = 0; cf < 4; ++cf) {
        int gf = wc * 2 + (cf & 1) + (cf >> 1) * 4;
        int col = n0 + gf * 16 + l15;
#pragma unroll
        for (int r = 0; r < 4; ++r) {
          int row = m0 + wr * 64 + rf * 16 + lgrp * 4 + r;
          Cout[(size_t)row * N + col] = acc[rf][cf][r];
        }
      }
  } else {
    const float FREQF = -0.14391156642f;  // -ln(10000)/64
#pragma unroll
    for (int rf = 0; rf < 4; ++rf) {
#pragma unroll
      for (int r = 0; r < 4; ++r) {
        int row = m0 + wr * 64 + rf * 16 + lgrp * 4 + r;
        int b_ = row >> 11, s = row & (SEQ - 1);
        if (n0 < NQK + NKVD) {  // q or k region: apply RoPE
          float pos = (float)positions[row];
#pragma unroll
          for (int cf = 0; cf < 2; ++cf) {
            int gf = wc * 2 + cf;
            int d1 = gf * 16 + l15;  // 0..63
            float ang = pos * expf((float)d1 * FREQF);
            float sn, cs;
            sincosf(ang, &sn, &cs);
            float x1 = acc[rf][cf][r], x2 = acc[rf][cf + 2][r];
            float o1 = x1 * cs - x2 * sn;
            float o2 = x1 * sn + x2 * cs;
            if (n0 < NQK) {
              int h = n0 >> 7;
              size_t base = (((size_t)b_ * NHQ + h) * SEQ + s) * DHEAD;
              qout[base + d1] = f2h(o1);
              qout[base + d1 + 64] = f2h(o2);
            } else {
              int h = (n0 - NQK) >> 7;
              size_t base = (((size_t)b_ * NKVH + h) * SEQ + s) * DHEAD;
              kout[base + d1] = f2h(o1);
              kout[base + d1 + 64] = f2h(o2);
            }
          }
        } else {  // v region: store transposed [b][h][d][s]
          int h = (n0 - NQK - NKVD) >> 7;
          size_t base = ((size_t)b_ * NKVH + h) * DHEAD * SEQ;
#pragma unroll
          for (int cf = 0; cf < 4; ++cf) {
            int gf = wc * 2 + (cf & 1) + (cf >> 1) * 4;
            int d = gf * 16 + l15;
            vout[base + (size_t)d * SEQ + s] = f2h(acc[rf][cf][r]);
          }
        }
      }
    }
  }
}

// ---------------- GQA causal flash attention (R2 rework) ----------------
// Q [b][h][s][d]; K [b][hk][s][d]; Vt [b][hk][d][s]. Out [b][s][h*128+d] f16.
// Block handles q-tiles {qp, 31-qp} -> uniform 33 KV-tile iters. 4 blocks/CU.
__global__ __launch_bounds__(256, 4) void k_attn(const u16* __restrict__ Q,
                                                 const u16* __restrict__ Kc,
                                                 const u16* __restrict__ Vct,
                                                 u16* __restrict__ Oout) {
  __shared__ u16 Ks[64 * 136];   // [kv][d] pad 8; after QK, P [64][72] aliases here
  __shared__ u16 Vt[128 * 72];   // [d][kv] pad 8
  const int tid = threadIdx.x, w = tid >> 6, lane = tid & 63;
  const int lgrp = lane >> 4, l15 = lane & 15;
  // XCD-aware swizzle of flat block id (1024 blocks, 1024%8==0 -> bijective)
  const int id = blockIdx.x;
  const int sw = (id & 7) * 128 + (id >> 3);
  const int qp = sw & 15, h = (sw >> 4) & 31, b = sw >> 9;
  const int hk = h >> 2;  // GQA group = 4
  const size_t qbase = ((size_t)b * NHQ + h) * SEQ * DHEAD;
  const size_t kbase = ((size_t)b * NKVH + hk) * SEQ * DHEAD;
  const size_t vtbase = ((size_t)b * NKVH + hk) * DHEAD * SEQ;
  u16* Ps = Ks;  // P tile aliases K tile (valid after post-QK barrier)

#pragma unroll 1
  for (int pass = 0; pass < 2; ++pass) {
    const int qt = pass ? (31 - qp) : qp;
    const int q0 = qt * 64;
    half8 qf[4];
    {
      int qrow = q0 + w * 16 + l15;
#pragma unroll
      for (int df = 0; df < 4; ++df)
        qf[df] = *(const half8*)&Q[qbase + (size_t)qrow * DHEAD + df * 32 + lgrp * 8];
    }
    f32x4v O[8] = {};
    float mrow[4], lrow[4];
#pragma unroll
    for (int r = 0; r < 4; ++r) { mrow[r] = -3.0e38f; lrow[r] = 0.f; }

#pragma unroll 1
    for (int t = 0; t <= qt; ++t) {
      const int kv0 = t * 64;
      __syncthreads();  // prior tile's (and prior pass's) LDS reads complete
#pragma unroll
      for (int i = 0; i < 4; ++i) {  // stage K tile [64][128] -> padded 136
        int idx = i * 256 + tid;
        int kv = idx >> 4, c = idx & 15;
        int4 val = *(const int4*)&Kc[kbase + (size_t)(kv0 + kv) * DHEAD + c * 8];
        *(int4*)&Ks[kv * 136 + c * 8] = val;
      }
#pragma unroll
      for (int i = 0; i < 4; ++i) {  // stage V^T tile [128][64] -> padded 72
        int idx = i * 256 + tid;
        int d = idx >> 3, c = idx & 7;
        int4 val = *(const int4*)&Vct[vtbase + (size_t)d * SEQ + kv0 + c * 8];
        *(int4*)&Vt[d * 72 + c * 8] = val;
      }
      __syncthreads();

      f32x4v sa[4] = {};
      __builtin_amdgcn_s_setprio(1);
#pragma unroll
      for (int kvf = 0; kvf < 4; ++kvf)
#pragma unroll
        for (int df = 0; df < 4; ++df) {
          half8 kb = *(const half8*)&Ks[(kvf * 16 + l15) * 136 + df * 32 + lgrp * 8];
          sa[kvf] = __builtin_amdgcn_mfma_f32_16x16x32_f16(qf[df], kb, sa[kvf], 0, 0, 0);
        }
      __builtin_amdgcn_s_setprio(0);

      const float scale = 0.08838834764831845f;  // 1/sqrt(128)
      unsigned pv16[4][2];  // P packed to fp16 pairs: [r][kvf/2]
#pragma unroll
      for (int r = 0; r < 4; ++r) {
        float sv[4];
        float mx = -3.0e38f;
        if (t == qt) {  // diagonal tile: causal mask bites
          const int qa = q0 + w * 16 + lgrp * 4 + r;
#pragma unroll
          for (int kvf = 0; kvf < 4; ++kvf) {
            float x = sa[kvf][r] * scale;
            int ka = kv0 + kvf * 16 + l15;
            x = (ka > qa) ? -3.0e38f : x;
            sv[kvf] = x;
            mx = fmaxf(mx, x);
          }
        } else {
#pragma unroll
          for (int kvf = 0; kvf < 4; ++kvf) {
            float x = sa[kvf][r] * scale;
            sv[kvf] = x;
            mx = fmaxf(mx, x);
          }
        }
#pragma unroll
        for (int off = 1; off < 16; off <<= 1) mx = fmaxf(mx, __shfl_xor(mx, off, 64));
        float mnew = fmaxf(mrow[r], mx);
        float alpha = __expf(mrow[r] - mnew);
        mrow[r] = mnew;
        float rs = 0.f;
#pragma unroll
        for (int kvf = 0; kvf < 4; ++kvf) {
          float p = __expf(sv[kvf] - mnew);
          sv[kvf] = p;
          rs += p;
        }
#pragma unroll
        for (int off = 1; off < 16; off <<= 1) rs += __shfl_xor(rs, off, 64);
        lrow[r] = lrow[r] * alpha + rs;
#pragma unroll
        for (int nf = 0; nf < 8; ++nf) O[nf][r] *= alpha;
        pv16[r][0] = (unsigned)f2h(sv[0]) | ((unsigned)f2h(sv[1]) << 16);
        pv16[r][1] = (unsigned)f2h(sv[2]) | ((unsigned)f2h(sv[3]) << 16);
      }

      __syncthreads();  // all waves' QK reads of Ks done -> safe to overwrite with P
#pragma unroll
      for (int r = 0; r < 4; ++r) {
        int prow = (w * 16 + lgrp * 4 + r) * 72;
        Ps[prow + 0 * 16 + l15] = (u16)(pv16[r][0] & 0xffff);
        Ps[prow + 1 * 16 + l15] = (u16)(pv16[r][0] >> 16);
        Ps[prow + 2 * 16 + l15] = (u16)(pv16[r][1] & 0xffff);
        Ps[prow + 3 * 16 + l15] = (u16)(pv16[r][1] >> 16);
      }
      __syncthreads();  // P visible

      half8 pa[2];
#pragma unroll
      for (int k2 = 0; k2 < 2; ++k2)
        pa[k2] = *(const half8*)&Ps[(w * 16 + l15) * 72 + k2 * 32 + lgrp * 8];
      __builtin_amdgcn_s_setprio(1);
#pragma unroll
      for (int nf = 0; nf < 8; ++nf)
#pragma unroll
        for (int k2 = 0; k2 < 2; ++k2) {
          half8 vb = *(const half8*)&Vt[(nf * 16 + l15) * 72 + k2 * 32 + lgrp * 8];
          O[nf] = __builtin_amdgcn_mfma_f32_16x16x32_f16(pa[k2], vb, O[nf], 0, 0, 0);
        }
      __builtin_amdgcn_s_setprio(0);
    }

#pragma unroll
    for (int r = 0; r < 4; ++r) {
      float inv = 1.0f / lrow[r];
      int s = q0 + w * 16 + lgrp * 4 + r;
      size_t obase = ((size_t)b * SEQ + s) * NQK + h * DHEAD;
#pragma unroll
      for (int nf = 0; nf < 8; ++nf) Oout[obase + nf * 16 + l15] = f2h(O[nf][r] * inv);
    }
  }
}

// ---------------- launch ----------------
extern "C" void kernel_launch(void* const* d_in, const int* in_sizes, int n_in,
                              void* d_out, int out_size, void* d_ws, size_t ws_size,
                              hipStream_t stream) {
  const float* hs = (const float*)d_in[0];
  const float* wqkv = (const float*)d_in[1];
  const float* wo = (const float*)d_in[2];
  const int* positions = (const int*)d_in[3];
  float* out = (float*)d_out;
  char* ws = (char*)d_ws;

  u16* hs16  = (u16*)(ws);                    // 33,554,432 B
  u16* wqkvt = (u16*)(ws + 33554432);         // 50,331,648 B
  u16* q16   = (u16*)(ws + 83886080);         // 33,554,432 B
  u16* k16   = (u16*)(ws + 117440512);        //  8,388,608 B
  u16* v16t  = (u16*)(ws + 125829120);        //  8,388,608 B (end: 128 MiB)
  u16* wot    = (u16*)(ws);                   // reuse region 0 (hs16 dead after QKV gemm)
  u16* attn16 = (u16*)(ws + 33554432);        // reuse region 1 (wqkvt dead after QKV gemm)

  k_conv_hs<<<2048, 256, 0, stream>>>(hs, hs16, MROWS * HIDD / 8);
  k_transpose_f16<<<dim3(NTOT / 64, HIDD / 64), 256, 0, stream>>>(wqkv, wqkvt, HIDD, NTOT);
  k_gemm<0><<<dim3(NTOT / 128, MROWS / 128), 256, 0, stream>>>(
      hs16, wqkvt, MROWS, NTOT, HIDD, positions, q16, k16, v16t, nullptr);
  k_transpose_f16<<<dim3(HIDD / 64, NQK / 64), 256, 0, stream>>>(wo, wot, NQK, HIDD);
  k_attn<<<1024, 256, 0, stream>>>(q16, k16, v16t, attn16);
  k_gemm<1><<<dim3(HIDD / 128, MROWS / 128), 256, 0, stream>>>(
      attn16, wot, MROWS, HIDD, NQK, nullptr, nullptr, nullptr, nullptr, out);
}